// Round 3
// baseline (840.696 us; speedup 1.0000x reference)
//
#include <hip/hip_runtime.h>
#include <math.h>

#define CCH 48
#define NST 16
#define VOX (64*64*64)

__device__ __forceinline__ float softplus_f(float s) {
    return fmaxf(s, 0.f) + log1pf(__expf(-fabsf(s)));
}

template<int CTRL>
__device__ __forceinline__ float dpp_add(float x) {
    int v = __builtin_amdgcn_update_dpp(0, __float_as_int(x), CTRL, 0xF, 0xF, true);
    return x + __int_as_float(v);
}

__global__ __launch_bounds__(256) void k_transpose_in(const float* __restrict__ x,
                                                      float* __restrict__ xt) {
    __shared__ float tile[CCH * 65];
    int v0 = blockIdx.x * 64;
    int t = threadIdx.x;
#pragma unroll
    for (int i = 0; i < 12; ++i) {
        int idx = t + i * 256;
        int c = idx >> 6, v = idx & 63;
        tile[c * 65 + v] = x[c * VOX + v0 + v];
    }
    __syncthreads();
#pragma unroll
    for (int i = 0; i < 12; ++i) {
        int idx = t + i * 256;
        int v = idx / CCH, c = idx - v * CCH;
        xt[(v0 + v) * CCH + c] = tile[c * 65 + v];
    }
}

__global__ __launch_bounds__(256) void k_transpose_out(const float* __restrict__ yws,
                                                       float* __restrict__ out) {
    __shared__ float tile[CCH * 65];
    int v0 = blockIdx.x * 64;
    int t = threadIdx.x;
#pragma unroll
    for (int i = 0; i < 12; ++i) {
        int idx = t + i * 256;
        int v = idx / CCH, c = idx - v * CCH;
        tile[c * 65 + v] = yws[(v0 + v) * CCH + c];
    }
    __syncthreads();
#pragma unroll
    for (int i = 0; i < 12; ++i) {
        int idx = t + i * 256;
        int c = idx >> 6, v = idx & 63;
        out[c * VOX + v0 + v] = tile[c * 65 + v];
    }
}

// LDS layout (float offsets)
#define OFF_XS    0        // 3072  xs[l*48+c]
#define OFF_WDT   3072     // 2496  wdtT[c*52+k]
#define OFF_WB    5568     // 832   wBT[n*52+k]
#define OFF_WC    6400     // 832   wCT[n*52+k]
#define OFF_DTS   7232     // 3264  dtsT[c*68+l]
#define OFF_UX    10496    // 3264  uxT[c*68+l]
#define OFF_BC    13760    // 1024  BcsT[n*64+l]
#define OFF_CC    14784    // 1024  CcsT[n*64+l]
#define OFF_YS    3072     // 3072  ys[l*48+c]  (aliases wdtT/wBT after projections)
#define SMEM_FLOATS 15808  // 63,232 B -> 2 blocks/CU

__global__ __launch_bounds__(768, 6) void k_scan(
    const float* __restrict__ xt, float* __restrict__ yws,
    const float* __restrict__ A_log, const float* __restrict__ W_dt,
    const float* __restrict__ b_dt, const float* __restrict__ W_B,
    const float* __restrict__ W_C, const float* __restrict__ D_skip,
    int dir, int stride_v, int accumulate)
{
    __shared__ __align__(16) float smem[SMEM_FLOATS];
    float* xs   = smem + OFF_XS;
    float* wdtT = smem + OFF_WDT;
    float* wBT  = smem + OFF_WB;
    float* wCT  = smem + OFF_WC;
    float* dtsT = smem + OFF_DTS;
    float* uxT  = smem + OFF_UX;
    float* BcsT = smem + OFF_BC;
    float* CcsT = smem + OFF_CC;
    float* ys   = smem + OFF_YS;

    int t = threadIdx.x;
    int lid = blockIdx.x;
    int a = lid >> 6, b = lid & 63;
    int vbase;
    if (dir == 0) vbase = lid;                 // (h,w), step stride 4096 (along D)
    else if (dir == 1) vbase = a * 4096 + b;   // (d,w), step stride 64   (along H)
    else vbase = a * 4096 + b * 64;            // (d,h), step stride 1    (along W)

    const float* wdt_g = W_dt + dir * CCH * CCH;
    const float* wB_g  = W_B + dir * CCH * NST;
    const float* wC_g  = W_C + dir * CCH * NST;

    // ---- stage line of x (one float4 per thread) ----
    {
        int q = t % 12, l = t / 12;
        *(float4*)&xs[l * CCH + 4 * q] =
            *(const float4*)&xt[(vbase + l * stride_v) * CCH + 4 * q];
    }
    // ---- stage transposed weights ----
    for (int idx = t; idx < CCH * CCH; idx += 768) {
        int k = idx / CCH, c2 = idx - k * CCH;
        wdtT[c2 * 52 + k] = wdt_g[idx];
    }
    {
        int k = t >> 4, n2 = t & 15;
        wBT[n2 * 52 + k] = wB_g[t];
        wCT[n2 * 52 + k] = wC_g[t];
    }
    __syncthreads();

    // ---- dt projection: thread owns channel c, 4 positions l ----
    {
        int c = t % CCH;
        int l0 = t / CCH;
        float bc = b_dt[dir * CCH + c];
        const float4* wr = (const float4*)&wdtT[c * 52];
#pragma unroll
        for (int i = 0; i < 4; ++i) {
            int l = l0 + 16 * i;
            const float4* xr = (const float4*)&xs[l * CCH];
            float s = bc;
#pragma unroll
            for (int q = 0; q < 12; ++q) {
                float4 xv = xr[q];
                float4 wv = wr[q];
                s = fmaf(xv.x, wv.x, s);
                s = fmaf(xv.y, wv.y, s);
                s = fmaf(xv.z, wv.z, s);
                s = fmaf(xv.w, wv.w, s);
            }
            float spv = softplus_f(s);
            dtsT[c * 68 + l] = spv;
            uxT[c * 68 + l]  = spv * xs[l * CCH + c];
        }
    }
    // ---- B and C projections: thread owns (n, l) ----
    {
        int n = t & 15;
        int lA = t >> 4;
#pragma unroll
        for (int rep = 0; rep < 2; ++rep) {
            int l = (rep == 0) ? lA : (48 + lA);
            if (rep == 0 || t < 256) {
                const float4* xr  = (const float4*)&xs[l * CCH];
                const float4* wbr = (const float4*)&wBT[n * 52];
                const float4* wcr = (const float4*)&wCT[n * 52];
                float sB = 0.f, sC = 0.f;
#pragma unroll
                for (int q = 0; q < 12; ++q) {
                    float4 xv = xr[q];
                    float4 wb = wbr[q];
                    float4 wc = wcr[q];
                    sB = fmaf(xv.x, wb.x, sB); sC = fmaf(xv.x, wc.x, sC);
                    sB = fmaf(xv.y, wb.y, sB); sC = fmaf(xv.y, wc.y, sC);
                    sB = fmaf(xv.z, wb.z, sB); sC = fmaf(xv.z, wc.z, sC);
                    sB = fmaf(xv.w, wb.w, sB); sC = fmaf(xv.w, wc.w, sC);
                }
                BcsT[n * 64 + l] = sB;
                CcsT[n * 64 + l] = sC;
            }
        }
    }
    __syncthreads();

    // ---- sequential scan: thread owns state (c,n) ----
    {
        int cc = t >> 4, n = t & 15;
        float a_cn = -expf(A_log[dir * CCH * NST + cc * NST + n]);
        const float4* dt4 = (const float4*)&dtsT[cc * 68];
        const float4* ux4 = (const float4*)&uxT[cc * 68];
        const float4* B4  = (const float4*)&BcsT[n * 64];
        const float4* C4  = (const float4*)&CcsT[n * 64];
        float h = 0.f;

#define STEP(COMP, LIDX)                                                    \
        h = fmaf(__expf(dtv.COMP * a_cn), h, uxv.COMP * Bv.COMP);           \
        {                                                                   \
            float p = h * Cv.COMP;                                          \
            p = dpp_add<0x121>(p);                                          \
            p = dpp_add<0x122>(p);                                          \
            p = dpp_add<0x124>(p);                                          \
            p = dpp_add<0x128>(p);                                          \
            if (n == 0) ys[(LIDX) * CCH + cc] = p;                          \
        }

#pragma unroll
        for (int l4 = 0; l4 < 16; ++l4) {
            float4 dtv = dt4[l4];
            float4 uxv = ux4[l4];
            float4 Bv  = B4[l4];
            float4 Cv  = C4[l4];
            STEP(x, l4 * 4 + 0)
            STEP(y, l4 * 4 + 1)
            STEP(z, l4 * 4 + 2)
            STEP(w, l4 * 4 + 3)
        }
#undef STEP
    }
    __syncthreads();

    // ---- add skip term and write/accumulate to yws ----
    {
        int q = t % 12, l = t / 12;
        float4 yv = *(const float4*)&ys[l * CCH + 4 * q];
        float4 xv = *(const float4*)&xs[l * CCH + 4 * q];
        float4 dv = *(const float4*)&D_skip[dir * CCH + 4 * q];
        yv.x = fmaf(dv.x, xv.x, yv.x);
        yv.y = fmaf(dv.y, xv.y, yv.y);
        yv.z = fmaf(dv.z, xv.z, yv.z);
        yv.w = fmaf(dv.w, xv.w, yv.w);
        float* gp = &yws[(vbase + l * stride_v) * CCH + 4 * q];
        if (accumulate) {
            float4 old = *(const float4*)gp;
            yv.x += old.x; yv.y += old.y; yv.z += old.z; yv.w += old.w;
        }
        *(float4*)gp = yv;
    }
}

extern "C" void kernel_launch(void* const* d_in, const int* in_sizes, int n_in,
                              void* d_out, int out_size, void* d_ws, size_t ws_size,
                              hipStream_t stream) {
    const float* x      = (const float*)d_in[0];
    const float* A_log  = (const float*)d_in[1];
    const float* W_dt   = (const float*)d_in[2];
    const float* b_dt   = (const float*)d_in[3];
    const float* W_B    = (const float*)d_in[4];
    const float* W_C    = (const float*)d_in[5];
    const float* D_skip = (const float*)d_in[6];
    float* out = (float*)d_out;

    float* xt  = (float*)d_ws;
    float* yws = xt + (size_t)VOX * CCH;

    k_transpose_in<<<VOX / 64, 256, 0, stream>>>(x, xt);
    k_scan<<<4096, 768, 0, stream>>>(xt, yws, A_log, W_dt, b_dt, W_B, W_C, D_skip, 0, 4096, 0);
    k_scan<<<4096, 768, 0, stream>>>(xt, yws, A_log, W_dt, b_dt, W_B, W_C, D_skip, 1, 64, 1);
    k_scan<<<4096, 768, 0, stream>>>(xt, yws, A_log, W_dt, b_dt, W_B, W_C, D_skip, 2, 1, 1);
    k_transpose_out<<<VOX / 64, 256, 0, stream>>>(yws, out);
}

// Round 5
// 403.155 us; speedup vs baseline: 2.0853x; 2.0853x over previous
//
#include <hip/hip_runtime.h>
#include <math.h>

#define CCH 48
#define NST 16
#define VOX (64*64*64)

__device__ __forceinline__ float softplus_f(float s) {
    return fmaxf(s, 0.f) + log1pf(__expf(-fabsf(s)));
}

template<int CTRL>
__device__ __forceinline__ float dpp_add(float x) {
    int v = __builtin_amdgcn_update_dpp(0, __float_as_int(x), CTRL, 0xF, 0xF, true);
    return x + __int_as_float(v);
}

__global__ __launch_bounds__(256) void k_transpose_in(const float* __restrict__ x,
                                                      float* __restrict__ xt) {
    __shared__ float tile[CCH * 65];
    int v0 = blockIdx.x * 64;
    int t = threadIdx.x;
#pragma unroll
    for (int i = 0; i < 12; ++i) {
        int idx = t + i * 256;
        int c = idx >> 6, v = idx & 63;
        tile[c * 65 + v] = x[c * VOX + v0 + v];
    }
    __syncthreads();
#pragma unroll
    for (int i = 0; i < 12; ++i) {
        int idx = t + i * 256;
        int v = idx / CCH, c = idx - v * CCH;
        xt[(v0 + v) * CCH + c] = tile[c * 65 + v];
    }
}

__global__ __launch_bounds__(256) void k_transpose_out(const float* __restrict__ yws,
                                                       float* __restrict__ out) {
    __shared__ float tile[CCH * 65];
    int v0 = blockIdx.x * 64;
    int t = threadIdx.x;
#pragma unroll
    for (int i = 0; i < 12; ++i) {
        int idx = t + i * 256;
        int v = idx / CCH, c = idx - v * CCH;
        tile[c * 65 + v] = yws[(v0 + v) * CCH + c];
    }
    __syncthreads();
#pragma unroll
    for (int i = 0; i < 12; ++i) {
        int idx = t + i * 256;
        int c = idx >> 6, v = idx & 63;
        out[c * VOX + v0 + v] = tile[c * 65 + v];
    }
}

// LDS layout (float offsets). All scan-phase row strides are 68 floats
// (68 ≡ 4 mod 32 banks -> row index spreads across bank groups; 16B aligned).
#define OFF_XS    0        // 3072  xs[l*48+c]
#define OFF_WDT   3072     // 2496  wdtT[c*52+k]
#define OFF_WB    5568     // 832   wBT[n*52+k]
#define OFF_WC    6400     // 832   wCT[n*52+k]
#define OFF_DTS   7232     // 3264  dtsT[c*68+l]
#define OFF_UX    10496    // 3264  uxT[c*68+l]
#define OFF_BC    13760    // 1088  BcsT[n*68+l]   (stride 64 -> 68: was 16-way conflict)
#define OFF_CC    14848    // 1088  CcsT[n*68+l]
#define OFF_YS    3072     // 3072  ys[l*48+c]  (aliases wdtT/wBT after projections)
#define SMEM_FLOATS 15936  // 63,744 B -> still 2 blocks/CU (127.5 KiB of 160)

__global__ __launch_bounds__(768, 6) void k_scan(
    const float* __restrict__ xt, float* __restrict__ yws,
    const float* __restrict__ A_log, const float* __restrict__ W_dt,
    const float* __restrict__ b_dt, const float* __restrict__ W_B,
    const float* __restrict__ W_C, const float* __restrict__ D_skip,
    int dir, int stride_v, int accumulate)
{
    __shared__ __align__(16) float smem[SMEM_FLOATS];
    float* xs   = smem + OFF_XS;
    float* wdtT = smem + OFF_WDT;
    float* wBT  = smem + OFF_WB;
    float* wCT  = smem + OFF_WC;
    float* dtsT = smem + OFF_DTS;
    float* uxT  = smem + OFF_UX;
    float* BcsT = smem + OFF_BC;
    float* CcsT = smem + OFF_CC;
    float* ys   = smem + OFF_YS;

    int t = threadIdx.x;
    int lid = blockIdx.x;
    int a = lid >> 6, b = lid & 63;
    int vbase;
    if (dir == 0) vbase = lid;                 // (h,w), step stride 4096 (along D)
    else if (dir == 1) vbase = a * 4096 + b;   // (d,w), step stride 64   (along H)
    else vbase = a * 4096 + b * 64;            // (d,h), step stride 1    (along W)

    const float* wdt_g = W_dt + dir * CCH * CCH;
    const float* wB_g  = W_B + dir * CCH * NST;
    const float* wC_g  = W_C + dir * CCH * NST;

    // ---- stage line of x (one float4 per thread) ----
    {
        int q = t % 12, l = t / 12;
        *(float4*)&xs[l * CCH + 4 * q] =
            *(const float4*)&xt[(vbase + l * stride_v) * CCH + 4 * q];
    }
    // ---- stage transposed weights ----
    for (int idx = t; idx < CCH * CCH; idx += 768) {
        int k = idx / CCH, c2 = idx - k * CCH;
        wdtT[c2 * 52 + k] = wdt_g[idx];
    }
    {
        int k = t >> 4, n2 = t & 15;
        wBT[n2 * 52 + k] = wB_g[t];
        wCT[n2 * 52 + k] = wC_g[t];
    }
    __syncthreads();

    // ---- dt projection: thread owns channel c, 4 CONSECUTIVE positions ----
    // float4 writes to dtsT/uxT: bank-group = (c + l0) mod 8 -> conflict-free.
    {
        int c  = t % CCH;
        int l0 = t / CCH;                      // 0..15, l = 4*l0 + i
        float bc = b_dt[dir * CCH + c];
        const float4* wr  = (const float4*)&wdtT[c * 52];
        const float4* xr0 = (const float4*)&xs[(4 * l0 + 0) * CCH];
        const float4* xr1 = (const float4*)&xs[(4 * l0 + 1) * CCH];
        const float4* xr2 = (const float4*)&xs[(4 * l0 + 2) * CCH];
        const float4* xr3 = (const float4*)&xs[(4 * l0 + 3) * CCH];
        float s0 = bc, s1 = bc, s2 = bc, s3 = bc;
#pragma unroll
        for (int q = 0; q < 12; ++q) {
            float4 wv = wr[q];
            float4 x0 = xr0[q], x1 = xr1[q], x2 = xr2[q], x3 = xr3[q];
            s0 = fmaf(x0.x, wv.x, s0); s0 = fmaf(x0.y, wv.y, s0);
            s0 = fmaf(x0.z, wv.z, s0); s0 = fmaf(x0.w, wv.w, s0);
            s1 = fmaf(x1.x, wv.x, s1); s1 = fmaf(x1.y, wv.y, s1);
            s1 = fmaf(x1.z, wv.z, s1); s1 = fmaf(x1.w, wv.w, s1);
            s2 = fmaf(x2.x, wv.x, s2); s2 = fmaf(x2.y, wv.y, s2);
            s2 = fmaf(x2.z, wv.z, s2); s2 = fmaf(x2.w, wv.w, s2);
            s3 = fmaf(x3.x, wv.x, s3); s3 = fmaf(x3.y, wv.y, s3);
            s3 = fmaf(x3.z, wv.z, s3); s3 = fmaf(x3.w, wv.w, s3);
        }
        float4 dtv, uxv;
        dtv.x = softplus_f(s0); uxv.x = dtv.x * xs[(4 * l0 + 0) * CCH + c];
        dtv.y = softplus_f(s1); uxv.y = dtv.y * xs[(4 * l0 + 1) * CCH + c];
        dtv.z = softplus_f(s2); uxv.z = dtv.z * xs[(4 * l0 + 2) * CCH + c];
        dtv.w = softplus_f(s3); uxv.w = dtv.w * xs[(4 * l0 + 3) * CCH + c];
        *(float4*)&dtsT[c * 68 + 4 * l0] = dtv;
        *(float4*)&uxT[c * 68 + 4 * l0]  = uxv;
    }
    // ---- B and C projections: thread owns (n, l); stride-68 rows ----
    {
        int n = t & 15;
        int lA = t >> 4;
#pragma unroll
        for (int rep = 0; rep < 2; ++rep) {
            int l = (rep == 0) ? lA : (48 + lA);
            if (rep == 0 || t < 256) {
                const float4* xr  = (const float4*)&xs[l * CCH];
                const float4* wbr = (const float4*)&wBT[n * 52];
                const float4* wcr = (const float4*)&wCT[n * 52];
                float sB = 0.f, sC = 0.f;
#pragma unroll
                for (int q = 0; q < 12; ++q) {
                    float4 xv = xr[q];
                    float4 wb = wbr[q];
                    float4 wc = wcr[q];
                    sB = fmaf(xv.x, wb.x, sB); sC = fmaf(xv.x, wc.x, sC);
                    sB = fmaf(xv.y, wb.y, sB); sC = fmaf(xv.y, wc.y, sC);
                    sB = fmaf(xv.z, wb.z, sB); sC = fmaf(xv.z, wc.z, sC);
                    sB = fmaf(xv.w, wb.w, sB); sC = fmaf(xv.w, wc.w, sC);
                }
                BcsT[n * 68 + l] = sB;
                CcsT[n * 68 + l] = sC;
            }
        }
    }
    __syncthreads();

    // ---- sequential scan: thread owns state (c,n) ----
    {
        int cc = t >> 4, n = t & 15;
        float a_cn = -expf(A_log[dir * CCH * NST + cc * NST + n]);
        const float4* dt4 = (const float4*)&dtsT[cc * 68];
        const float4* ux4 = (const float4*)&uxT[cc * 68];
        const float4* B4  = (const float4*)&BcsT[n * 68];
        const float4* C4  = (const float4*)&CcsT[n * 68];
        float h = 0.f;

#define STEP(COMP, LIDX)                                                    \
        h = fmaf(__expf(dtv.COMP * a_cn), h, uxv.COMP * Bv.COMP);           \
        {                                                                   \
            float p = h * Cv.COMP;                                          \
            p = dpp_add<0x121>(p);                                          \
            p = dpp_add<0x122>(p);                                          \
            p = dpp_add<0x124>(p);                                          \
            p = dpp_add<0x128>(p);                                          \
            if (n == 0) ys[(LIDX) * CCH + cc] = p;                          \
        }

#pragma unroll
        for (int l4 = 0; l4 < 16; ++l4) {
            float4 dtv = dt4[l4];
            float4 uxv = ux4[l4];
            float4 Bv  = B4[l4];
            float4 Cv  = C4[l4];
            STEP(x, l4 * 4 + 0)
            STEP(y, l4 * 4 + 1)
            STEP(z, l4 * 4 + 2)
            STEP(w, l4 * 4 + 3)
        }
#undef STEP
    }
    __syncthreads();

    // ---- add skip term and write/accumulate to yws ----
    {
        int q = t % 12, l = t / 12;
        float4 yv = *(const float4*)&ys[l * CCH + 4 * q];
        float4 xv = *(const float4*)&xs[l * CCH + 4 * q];
        float4 dv = *(const float4*)&D_skip[dir * CCH + 4 * q];
        yv.x = fmaf(dv.x, xv.x, yv.x);
        yv.y = fmaf(dv.y, xv.y, yv.y);
        yv.z = fmaf(dv.z, xv.z, yv.z);
        yv.w = fmaf(dv.w, xv.w, yv.w);
        float* gp = &yws[(vbase + l * stride_v) * CCH + 4 * q];
        if (accumulate) {
            float4 old = *(const float4*)gp;
            yv.x += old.x; yv.y += old.y; yv.z += old.z; yv.w += old.w;
        }
        *(float4*)gp = yv;
    }
}

extern "C" void kernel_launch(void* const* d_in, const int* in_sizes, int n_in,
                              void* d_out, int out_size, void* d_ws, size_t ws_size,
                              hipStream_t stream) {
    const float* x      = (const float*)d_in[0];
    const float* A_log  = (const float*)d_in[1];
    const float* W_dt   = (const float*)d_in[2];
    const float* b_dt   = (const float*)d_in[3];
    const float* W_B    = (const float*)d_in[4];
    const float* W_C    = (const float*)d_in[5];
    const float* D_skip = (const float*)d_in[6];
    float* out = (float*)d_out;

    float* xt  = (float*)d_ws;
    float* yws = xt + (size_t)VOX * CCH;

    k_transpose_in<<<VOX / 64, 256, 0, stream>>>(x, xt);
    k_scan<<<4096, 768, 0, stream>>>(xt, yws, A_log, W_dt, b_dt, W_B, W_C, D_skip, 0, 4096, 0);
    k_scan<<<4096, 768, 0, stream>>>(xt, yws, A_log, W_dt, b_dt, W_B, W_C, D_skip, 1, 64, 1);
    k_scan<<<4096, 768, 0, stream>>>(xt, yws, A_log, W_dt, b_dt, W_B, W_C, D_skip, 2, 1, 1);
    k_transpose_out<<<VOX / 64, 256, 0, stream>>>(yws, out);
}